// Round 9
// baseline (320.693 us; speedup 1.0000x reference)
//
#include <hip/hip_runtime.h>
#include <hip/hip_bf16.h>

#define Bb 8
#define Tt 4096
#define Dd 1024
#define Hh 1024
#define Mm (Bb * Tt)
#define NCHUNK 32
#define CLEN 128

typedef float f32x4 __attribute__((ext_vector_type(4)));
typedef short bf16x8 __attribute__((ext_vector_type(8)));

__device__ __forceinline__ unsigned f2bfu(float x) {
  unsigned u = __float_as_uint(x);
  return (u + 0x7fffu + ((u >> 16) & 1u)) >> 16;  // RNE to bf16 bits
}
__device__ __forceinline__ float bflo(unsigned u) { return __uint_as_float(u << 16); }
__device__ __forceinline__ float bfhi(unsigned u) { return __uint_as_float(u & 0xffff0000u); }

// ---------------- fp32 -> bf16 conversion (weights only now) ----------------
#define NW4 (Hh * Dd / 4)
__global__ void cvt_w_kernel(const float* __restrict__ wz,
                             const float* __restrict__ wh,
                             unsigned short* __restrict__ wzb,
                             unsigned short* __restrict__ whb) {
  const int n4 = 2 * NW4;
  int i = blockIdx.x * blockDim.x + threadIdx.x;
  const int stride = gridDim.x * blockDim.x;
  for (; i < n4; i += stride) {
    const float* src = (i < NW4) ? wz : wh;
    unsigned short* dst = (i < NW4) ? wzb : whb;
    const int j = (i < NW4) ? i : i - NW4;
    float4 v = reinterpret_cast<const float4*>(src)[j];
    ushort4 o;
    o.x = (unsigned short)f2bfu(v.x);
    o.y = (unsigned short)f2bfu(v.y);
    o.z = (unsigned short)f2bfu(v.z);
    o.w = (unsigned short)f2bfu(v.w);
    reinterpret_cast<ushort4*>(dst)[j] = o;
  }
}

__device__ __forceinline__ void async16(const unsigned short* g, unsigned short* l) {
  __builtin_amdgcn_global_load_lds(
      (const __attribute__((address_space(1))) unsigned int*)g,
      (__attribute__((address_space(3))) unsigned int*)l, 16, 0, 0);
}

// ordered affine compose across one lane-bit: segments (lo rows, hi rows)
#define SHFL_COMPOSE(A, Q, MASK, HIBIT)                                   \
  {                                                                       \
    const float pA_ = __shfl_xor(A, MASK);                                \
    const float pQ_ = __shfl_xor(Q, MASK);                                \
    const float Alo_ = (HIBIT) ? pA_ : A;                                 \
    const float Qlo_ = (HIBIT) ? pQ_ : Q;                                 \
    const float Ahi_ = (HIBIT) ? A : pA_;                                 \
    const float Qhi_ = (HIBIT) ? Q : pQ_;                                 \
    A = Alo_ * Ahi_;                                                      \
    Q = fmaf(Ahi_, Qlo_, Qhi_);                                           \
  }

// =====================================================================
// 128x256 tile, 8 waves (2M x 4N) of 64x64; acc 64 AGPR; 72 KiB LDS.
// A is read from x AS FP32 (global->reg, 2 dwordx4/thread/step),
// converted in-register (RNE, bit-identical to the old cvt pass) and
// ds_write_b128'd into the swizzled A layout at END of body (2nd
// vmcnt(2) after MFMA -> load regs are body-transient). B staged via
// global_load_lds as before. Wait discipline (induction-verified):
// per body issues [2 A-loads, 2 B-DMA]; end vmcnt(2) retires B(s) and
// A(s+2), leaves B(s+2); step top needs only lgkmcnt(0)+barrier.
// Tail A-loads (k>=1024) clamped to row base (no OOB read of x);
// B overrun lands in mapped ws. launch_bounds(512,3): no spill ever;
// 2 blocks/CU retained iff regs <= 128.
// Epilogue fuses gate transform + per-chunk scan reduction (pass1).
// =====================================================================
__global__ void __launch_bounds__(512, 3) gemm_kernel(
    const float* __restrict__ x,
    const unsigned short* __restrict__ wzb,
    const unsigned short* __restrict__ whb,
    const float* __restrict__ bz,
    const float* __restrict__ bh,
    unsigned int* __restrict__ P,
    float* __restrict__ Pp, float* __restrict__ Qq) {
  __shared__ unsigned short lds[36864];  // 72 KiB
  const int tid = threadIdx.x;
  const int wid = tid >> 6;
  const int wm = wid >> 2;      // 0..1
  const int wn = wid & 3;       // 0..3
  const int l = tid & 63, ln = l & 15, l4 = l >> 4;

  // bijective XCD swizzle (nwg=2048, divisible by 8)
  const int id = blockIdx.x;
  const int sw = (id & 7) * 256 + (id >> 3);
  const int mb = sw >> 3, nb = sw & 7;
  const int m0 = mb * 128, h0 = nb * 128;

  // ---- staging constants: thread t -> row r0 = t>>2, LDS slot t&3;
  // slot s at row r holds global k-chunk (s - (r>>1))&3 (R5 key) ----
  const int r0 = tid >> 2;
  const int chunk = ((tid & 3) - (tid >> 3)) & 3;
  const float* axbase = x + (size_t)(m0 + r0) * Dd + chunk * 8;
  const float* axp = axbase;
  const int sub16 = r0 >> 4;
  const int hrow0 = h0 + ((sub16 >> 1) << 4) + (r0 & 15);
  const unsigned short* bgp =
      ((sub16 & 1) ? whb : wzb) + (size_t)hrow0 * Dd + chunk * 8;
  const int ta = tid * 8;  // shorts; byte offset tid*16, 16B-aligned

  auto stageB = [&](int buf) {
    unsigned short* d = &lds[buf * 12288];
    async16(bgp, d + 4096 + ta);
    async16(bgp + (size_t)64 * Dd, d + 8192 + ta);  // n+128 -> h+64
    bgp += 32;
  };
  auto writeA = [&](int buf, const float4& v0, const float4& v1) {
    uint4 w;
    w.x = f2bfu(v0.x) | (f2bfu(v0.y) << 16);
    w.y = f2bfu(v0.z) | (f2bfu(v0.w) << 16);
    w.z = f2bfu(v1.x) | (f2bfu(v1.y) << 16);
    w.w = f2bfu(v1.z) | (f2bfu(v1.w) << 16);
    *reinterpret_cast<uint4*>(&lds[buf * 12288 + ta]) = w;
  };

  // ---- fragment read offsets (shorts within a buf) ----
  int oA[4], oB[4];
#pragma unroll
  for (int mf = 0; mf < 4; ++mf) {
    const int row = wm * 64 + mf * 16 + ln;
    const int sl = (l4 + (row >> 1)) & 3;
    oA[mf] = row * 32 + sl * 8;
  }
#pragma unroll
  for (int nf = 0; nf < 4; ++nf) {
    const int row = wn * 64 + nf * 16 + ln;
    const int sl = (l4 + (row >> 1)) & 3;
    oB[nf] = 4096 + row * 32 + sl * 8;
  }

  f32x4 acc[4][4];
#pragma unroll
  for (int i = 0; i < 4; ++i)
#pragma unroll
    for (int j = 0; j < 4; ++j) acc[i][j] = f32x4{0.f, 0.f, 0.f, 0.f};

  float4 av0, av1;

  // ---- prologue: A(0),B(0) then A(1),B(1); write A(0),A(1) ----
  av0 = *(const float4*)(axp);
  av1 = *(const float4*)(axp + 4);
  axp += 32;
  stageB(0);
  asm volatile("s_waitcnt vmcnt(2)" ::: "memory");  // A(0) done
  writeA(0, av0, av1);
  av0 = *(const float4*)(axp);
  av1 = *(const float4*)(axp + 4);
  axp += 32;
  stageB(1);
  asm volatile("s_waitcnt vmcnt(2)" ::: "memory");  // B(0), A(1) done
  writeA(1, av0, av1);

  int cur = 0, nxt = 2;
#pragma unroll 1
  for (int s = 0; s < 32; ++s) {
    asm volatile("s_waitcnt lgkmcnt(0)" ::: "memory");  // ds_writes visible
    __builtin_amdgcn_s_barrier();
    const unsigned short* bp = &lds[cur * 12288];
    bf16x8 af[4], bf[4];
    af[0] = *(const bf16x8*)(bp + oA[0]);
    af[1] = *(const bf16x8*)(bp + oA[1]);
    af[2] = *(const bf16x8*)(bp + oA[2]);
    af[3] = *(const bf16x8*)(bp + oA[3]);
    bf[0] = *(const bf16x8*)(bp + oB[0]);
    bf[1] = *(const bf16x8*)(bp + oB[1]);
    bf[2] = *(const bf16x8*)(bp + oB[2]);
    bf[3] = *(const bf16x8*)(bp + oB[3]);
    // issue A(s+2) fp32 loads (clamped at tail: data unused) + B(s+2) DMA
    const float* ap = (s < 30) ? axp : axbase;
    av0 = *(const float4*)(ap);
    av1 = *(const float4*)(ap + 4);
    axp += 32;
    stageB(nxt);  // overruns past k=1024 on last 2 steps: mapped ws, unused
    __builtin_amdgcn_s_setprio(1);
#pragma unroll
    for (int i = 0; i < 4; ++i)
#pragma unroll
      for (int j = 0; j < 4; ++j)
        acc[i][j] =
            __builtin_amdgcn_mfma_f32_16x16x32_bf16(af[i], bf[j], acc[i][j], 0, 0, 0);
    __builtin_amdgcn_s_setprio(0);
    // retire B(s) + A(s+2); leave B(s+2) in flight; write A(s+2).
    // Write target buf[(s+2)%3] == buf[(s-1)%3]: its readers finished
    // before this step's top barrier -> safe.
    asm volatile("s_waitcnt vmcnt(2)" ::: "memory");
    writeA(nxt, av0, av1);
    cur = (cur + 1) == 3 ? 0 : cur + 1;
    nxt = (nxt + 1) == 3 ? 0 : nxt + 1;
  }

  // drain pending B-DMA (incl. overrun stages) then sync before LDS
  // scratch reuse in the epilogue.
  asm volatile("s_waitcnt vmcnt(0)" ::: "memory");
  __syncthreads();

  float* sA = (float*)lds;        // [2][128] per-wm chunk-half A
  float* sQ = (float*)lds + 256;  // [2][128] per-wm chunk-half Q
  const int b_idx = mb >> 5;      // batch
  const int ch = mb & 31;         // scan chunk within batch

  // Epilogue: C/D layout col=lane&15, row=(lane>>4)*4+q.
  // nf pair (2p, 2p+1) = (k, pre) for hcol = h0 + (wn*2+p)*16 + ln.
  // Also compose the 64-row affine (A,Q) per column (bf16-rounded a,c —
  // bit-identical to a pass1 over P).
#pragma unroll
  for (int p = 0; p < 2; ++p) {
    const int hcol = h0 + (wn * 2 + p) * 16 + ln;
    const float bzv = bz[hcol];
    const float bhv = bh[hcol];
    float Ar = 1.f, Qr = 0.f;
#pragma unroll
    for (int mf = 0; mf < 4; ++mf) {
      float A4 = 1.f, Q4 = 0.f;
#pragma unroll
      for (int q = 0; q < 4; ++q) {
        const int m = m0 + wm * 64 + mf * 16 + l4 * 4 + q;
        const float kv = acc[mf][2 * p][q] + bzv;
        const float pv = acc[mf][2 * p + 1][q] + bhv;
        const float ek = __expf(kv);
        const float a = 1.f / (1.f + ek);   // 1 - sigmoid(k)
        const float z = 1.f - a;            // sigmoid(k)
        const float g = (pv >= 0.f) ? (pv + 0.5f) : (1.f / (1.f + __expf(-pv)));
        const float c = z * g;
        const unsigned pw = f2bfu(a) | (f2bfu(c) << 16);
        P[(size_t)m * Hh + hcol] = pw;
        const float ar = bflo(pw), cr = bfhi(pw);
        Q4 = fmaf(ar, Q4, cr);  // rows ascending (q)
        A4 *= ar;
      }
      SHFL_COMPOSE(A4, Q4, 16, (l4 & 1));        // row bit2
      SHFL_COMPOSE(A4, Q4, 32, ((l4 >> 1) & 1)); // row bit3 -> seg16(mf)
      Qr = fmaf(A4, Qr, Q4);  // compose seg16s in mf order
      Ar *= A4;
    }
    if (l4 == 0) {
      sA[wm * 128 + (wn * 2 + p) * 16 + ln] = Ar;
      sQ[wm * 128 + (wn * 2 + p) * 16 + ln] = Qr;
    }
  }
  __syncthreads();
  if (tid < 128) {
    const float A0 = sA[tid], Q0 = sQ[tid];
    const float A1 = sA[128 + tid], Q1 = sQ[128 + tid];
    const int idx = ch * (Bb * Hh) + b_idx * Hh + (h0 + tid);
    Pp[idx] = A0 * A1;                 // rows 0-63 then 64-127
    Qq[idx] = fmaf(A1, Q0, Q1);
  }
}

// ---------------- scan pass 2: sequential chunk combine (tiny) ----------------
__global__ void scan_pass2(const float* __restrict__ h0raw,
                           const float* __restrict__ Pp, const float* __restrict__ Qq,
                           float* __restrict__ Hinit) {
  const int bh = blockIdx.x * 256 + threadIdx.x;  // 0..8191
  const float x = h0raw[bh];
  float hs = (x >= 0.f) ? (x + 0.5f) : (1.f / (1.f + __expf(-x)));  // g(h_0)
  for (int ch = 0; ch < NCHUNK; ++ch) {
    const int idx = ch * (Bb * Hh) + bh;
    Hinit[idx] = hs;
    hs = fmaf(Pp[idx], hs, Qq[idx]);
  }
}

// ---------------- scan pass 3: in-chunk scan, write outputs ----------------
__global__ void scan_pass3(const unsigned int* __restrict__ P,
                           const float* __restrict__ Hinit,
                           float* __restrict__ out) {
  const int h = blockIdx.x * 256 + threadIdx.x;
  const int ch = blockIdx.y;
  const int b = blockIdx.z;
  float hs = Hinit[ch * (Bb * Hh) + b * Hh + h];
  const size_t base = ((size_t)(b * Tt + ch * CLEN)) * Hh + h;
  const unsigned int* p = P + base;
  float* o = out + base;
#pragma unroll 8
  for (int i = 0; i < CLEN; ++i) {
    const unsigned u = p[(size_t)i * Hh];
    hs = fmaf(bflo(u), hs, bfhi(u));
    o[(size_t)i * Hh] = hs;
  }
}

extern "C" void kernel_launch(void* const* d_in, const int* in_sizes, int n_in,
                              void* d_out, int out_size, void* d_ws, size_t ws_size,
                              hipStream_t stream) {
  const float* x  = (const float*)d_in[0];
  const float* h0 = (const float*)d_in[1];
  const float* Wz = (const float*)d_in[2];
  const float* bz = (const float*)d_in[3];
  const float* Wh = (const float*)d_in[4];
  const float* bh = (const float*)d_in[5];
  float* out = (float*)d_out;

  char* ws = (char*)d_ws;
  unsigned short* wzb = (unsigned short*)(ws + 67108864);            // 2 MiB
  unsigned short* whb = (unsigned short*)(ws + 69206016);            // 2 MiB
  unsigned int*   P   = (unsigned int*)(ws + 71303168);              // 128 MiB
  float* Pp    = (float*)(ws + 205520896);                           // 1 MiB
  float* Qq    = (float*)(ws + 206569472);                           // 1 MiB
  float* Hinit = (float*)(ws + 207618048);                           // 1 MiB

  cvt_w_kernel<<<1024, 256, 0, stream>>>(Wz, Wh, wzb, whb);

  gemm_kernel<<<2048, 512, 0, stream>>>(x, wzb, whb, bz, bh, P, Pp, Qq);

  scan_pass2<<<Bb * Hh / 256, 256, 0, stream>>>(h0, Pp, Qq, Hinit);
  dim3 sgrid(Hh / 256, NCHUNK, Bb);
  scan_pass3<<<sgrid, 256, 0, stream>>>(P, Hinit, out);
}

// Round 10
// 259.011 us; speedup vs baseline: 1.2381x; 1.2381x over previous
//
#include <hip/hip_runtime.h>
#include <hip/hip_bf16.h>

#define Bb 8
#define Tt 4096
#define Dd 1024
#define Hh 1024
#define Mm (Bb * Tt)
#define NCHUNK 32
#define CLEN 128

typedef float f32x4 __attribute__((ext_vector_type(4)));
typedef short bf16x8 __attribute__((ext_vector_type(8)));

__device__ __forceinline__ unsigned f2bfu(float x) {
  unsigned u = __float_as_uint(x);
  return (u + 0x7fffu + ((u >> 16) & 1u)) >> 16;  // RNE to bf16 bits
}
__device__ __forceinline__ float bflo(unsigned u) { return __uint_as_float(u << 16); }
__device__ __forceinline__ float bfhi(unsigned u) { return __uint_as_float(u & 0xffff0000u); }

// ---------------- fp32 -> bf16 conversion, all three arrays, one launch ----
#define NX4 (Mm * Dd / 4)
#define NW4 (Hh * Dd / 4)
__global__ void cvt_all_kernel(const float* __restrict__ x,
                               const float* __restrict__ wz,
                               const float* __restrict__ wh,
                               unsigned short* __restrict__ xb,
                               unsigned short* __restrict__ wzb,
                               unsigned short* __restrict__ whb) {
  const int n4 = NX4 + 2 * NW4;
  int i = blockIdx.x * blockDim.x + threadIdx.x;
  const int stride = gridDim.x * blockDim.x;
  for (; i < n4; i += stride) {
    const float* src;
    unsigned short* dst;
    int j = i;
    if (j < NX4) {
      src = x; dst = xb;
    } else if (j < NX4 + NW4) {
      j -= NX4; src = wz; dst = wzb;
    } else {
      j -= NX4 + NW4; src = wh; dst = whb;
    }
    float4 v = reinterpret_cast<const float4*>(src)[j];
    ushort4 o;
    o.x = (unsigned short)f2bfu(v.x);
    o.y = (unsigned short)f2bfu(v.y);
    o.z = (unsigned short)f2bfu(v.z);
    o.w = (unsigned short)f2bfu(v.w);
    reinterpret_cast<ushort4*>(dst)[j] = o;
  }
}

__device__ __forceinline__ void async16(const unsigned short* g, unsigned short* l) {
  __builtin_amdgcn_global_load_lds(
      (const __attribute__((address_space(1))) unsigned int*)g,
      (__attribute__((address_space(3))) unsigned int*)l, 16, 0, 0);
}

// ordered affine compose across one lane-bit: segments (lo rows, hi rows)
#define SHFL_COMPOSE(A, Q, MASK, HIBIT)                                   \
  {                                                                       \
    const float pA_ = __shfl_xor(A, MASK);                                \
    const float pQ_ = __shfl_xor(Q, MASK);                                \
    const float Alo_ = (HIBIT) ? pA_ : A;                                 \
    const float Qlo_ = (HIBIT) ? pQ_ : Q;                                 \
    const float Ahi_ = (HIBIT) ? A : pA_;                                 \
    const float Qhi_ = (HIBIT) ? Q : pQ_;                                 \
    A = Alo_ * Ahi_;                                                      \
    Q = fmaf(Ahi_, Qlo_, Qhi_);                                           \
  }

// =====================================================================
// 128x256 tile, 8 waves (2M x 4N) of 64x64; acc 64 AGPR; 72 KiB LDS ->
// 2 blocks/CU. Counted vmcnt (stage 2-ahead), 1 barrier per K-step.
// Swizzle: R5 key (slot = (l4 + (row>>1)) & 3) - measured 0 bank
// conflicts (R6's row key measured 16.8M).
// Epilogue fuses gate transform + per-chunk scan reduction (pass1).
// =====================================================================
__global__ void __launch_bounds__(512, 4) gemm_kernel(
    const unsigned short* __restrict__ xb,
    const unsigned short* __restrict__ wzb,
    const unsigned short* __restrict__ whb,
    const float* __restrict__ bz,
    const float* __restrict__ bh,
    unsigned int* __restrict__ P,
    float* __restrict__ Pp, float* __restrict__ Qq) {
  __shared__ unsigned short lds[36864];  // 72 KiB
  const int tid = threadIdx.x;
  const int wid = tid >> 6;
  const int wm = wid >> 2;      // 0..1
  const int wn = wid & 3;       // 0..3
  const int l = tid & 63, ln = l & 15, l4 = l >> 4;

  // bijective XCD swizzle (nwg=2048, divisible by 8)
  const int id = blockIdx.x;
  const int sw = (id & 7) * 256 + (id >> 3);
  const int mb = sw >> 3, nb = sw & 7;
  const int m0 = mb * 128, h0 = nb * 128;

  // ---- staging constants: thread t -> row r0 = t>>2, LDS slot t&3;
  // slot s at row r holds global k-chunk (s - (r>>1))&3 ----
  const int r0 = tid >> 2;
  const int chunk = ((tid & 3) - (tid >> 3)) & 3;
  const unsigned short* agp = xb + (size_t)(m0 + r0) * Dd + chunk * 8;
  const int sub16 = r0 >> 4;
  const int hrow0 = h0 + ((sub16 >> 1) << 4) + (r0 & 15);
  const unsigned short* bgp =
      ((sub16 & 1) ? whb : wzb) + (size_t)hrow0 * Dd + chunk * 8;
  const int ta = tid * 8;

  auto stage = [&](int buf) {
    unsigned short* d = &lds[buf * 12288];
    async16(agp, d + ta);
    async16(bgp, d + 4096 + ta);
    async16(bgp + (size_t)64 * Dd, d + 8192 + ta);  // n+128 -> h+64
    agp += 32;
    bgp += 32;
  };

  // ---- fragment read offsets (shorts within a buf) ----
  int oA[4], oB[4];
#pragma unroll
  for (int mf = 0; mf < 4; ++mf) {
    const int row = wm * 64 + mf * 16 + ln;
    const int sl = (l4 + (row >> 1)) & 3;
    oA[mf] = row * 32 + sl * 8;
  }
#pragma unroll
  for (int nf = 0; nf < 4; ++nf) {
    const int row = wn * 64 + nf * 16 + ln;
    const int sl = (l4 + (row >> 1)) & 3;
    oB[nf] = 4096 + row * 32 + sl * 8;
  }

  f32x4 acc[4][4];
#pragma unroll
  for (int i = 0; i < 4; ++i)
#pragma unroll
    for (int j = 0; j < 4; ++j) acc[i][j] = f32x4{0.f, 0.f, 0.f, 0.f};

  // ---- prologue: stage buf0, buf1 (6 vmem ops) ----
  stage(0);
  stage(1);

  int cur = 0, nxt = 2;
#pragma unroll 1
  for (int s = 0; s < 32; ++s) {
    asm volatile("s_waitcnt vmcnt(3)" ::: "memory");  // buf[cur] ready
    __builtin_amdgcn_s_barrier();
    const unsigned short* bp = &lds[cur * 12288];
    bf16x8 af[4], bf[4];
    af[0] = *(const bf16x8*)(bp + oA[0]);
    af[1] = *(const bf16x8*)(bp + oA[1]);
    af[2] = *(const bf16x8*)(bp + oA[2]);
    af[3] = *(const bf16x8*)(bp + oA[3]);
    bf[0] = *(const bf16x8*)(bp + oB[0]);
    bf[1] = *(const bf16x8*)(bp + oB[1]);
    bf[2] = *(const bf16x8*)(bp + oB[2]);
    bf[3] = *(const bf16x8*)(bp + oB[3]);
    stage(nxt);  // overruns past k=1024 on last 2 steps: mapped, unused
    __builtin_amdgcn_s_setprio(1);
#pragma unroll
    for (int i = 0; i < 4; ++i)
#pragma unroll
      for (int j = 0; j < 4; ++j)
        acc[i][j] =
            __builtin_amdgcn_mfma_f32_16x16x32_bf16(af[i], bf[j], acc[i][j], 0, 0, 0);
    __builtin_amdgcn_s_setprio(0);
    cur = (cur + 1) == 3 ? 0 : cur + 1;
    nxt = (nxt + 1) == 3 ? 0 : nxt + 1;
  }

  // drain pending LDS-DMA (incl. overrun stages) then sync before LDS
  // scratch reuse: another wave's DMA may target buf regions.
  asm volatile("s_waitcnt vmcnt(0)" ::: "memory");
  __syncthreads();

  float* sA = (float*)lds;        // [2][128] per-wm chunk-half A
  float* sQ = (float*)lds + 256;  // [2][128] per-wm chunk-half Q
  const int b_idx = mb >> 5;      // batch
  const int ch = mb & 31;         // scan chunk within batch

  // Epilogue: C/D layout col=lane&15, row=(lane>>4)*4+q.
  // nf pair (2p, 2p+1) = (k, pre) for hcol = h0 + (wn*2+p)*16 + ln.
  // Also compose the 64-row affine (A,Q) per column (bf16-rounded a,c —
  // bit-identical to a pass1 over P).
#pragma unroll
  for (int p = 0; p < 2; ++p) {
    const int hcol = h0 + (wn * 2 + p) * 16 + ln;
    const float bzv = bz[hcol];
    const float bhv = bh[hcol];
    float Ar = 1.f, Qr = 0.f;
#pragma unroll
    for (int mf = 0; mf < 4; ++mf) {
      float A4 = 1.f, Q4 = 0.f;
#pragma unroll
      for (int q = 0; q < 4; ++q) {
        const int m = m0 + wm * 64 + mf * 16 + l4 * 4 + q;
        const float kv = acc[mf][2 * p][q] + bzv;
        const float pv = acc[mf][2 * p + 1][q] + bhv;
        const float ek = __expf(kv);
        const float a = 1.f / (1.f + ek);   // 1 - sigmoid(k)
        const float z = 1.f - a;            // sigmoid(k)
        const float g = (pv >= 0.f) ? (pv + 0.5f) : (1.f / (1.f + __expf(-pv)));
        const float c = z * g;
        const unsigned pw = f2bfu(a) | (f2bfu(c) << 16);
        P[(size_t)m * Hh + hcol] = pw;
        const float ar = bflo(pw), cr = bfhi(pw);
        Q4 = fmaf(ar, Q4, cr);  // rows ascending (q)
        A4 *= ar;
      }
      SHFL_COMPOSE(A4, Q4, 16, (l4 & 1));        // row bit2
      SHFL_COMPOSE(A4, Q4, 32, ((l4 >> 1) & 1)); // row bit3 -> seg16(mf)
      Qr = fmaf(A4, Qr, Q4);  // compose seg16s in mf order
      Ar *= A4;
    }
    if (l4 == 0) {
      sA[wm * 128 + (wn * 2 + p) * 16 + ln] = Ar;
      sQ[wm * 128 + (wn * 2 + p) * 16 + ln] = Qr;
    }
  }
  __syncthreads();
  if (tid < 128) {
    const float A0 = sA[tid], Q0 = sQ[tid];
    const float A1 = sA[128 + tid], Q1 = sQ[128 + tid];
    const int idx = ch * (Bb * Hh) + b_idx * Hh + (h0 + tid);
    Pp[idx] = A0 * A1;                 // rows 0-63 then 64-127
    Qq[idx] = fmaf(A1, Q0, Q1);
  }
}

// ---------------- scan pass 2: sequential chunk combine (tiny) ----------------
__global__ void scan_pass2(const float* __restrict__ h0raw,
                           const float* __restrict__ Pp, const float* __restrict__ Qq,
                           float* __restrict__ Hinit) {
  const int bh = blockIdx.x * 256 + threadIdx.x;  // 0..8191
  const float x = h0raw[bh];
  float hs = (x >= 0.f) ? (x + 0.5f) : (1.f / (1.f + __expf(-x)));  // g(h_0)
  for (int ch = 0; ch < NCHUNK; ++ch) {
    const int idx = ch * (Bb * Hh) + bh;
    Hinit[idx] = hs;
    hs = fmaf(Pp[idx], hs, Qq[idx]);
  }
}

// ---------------- scan pass 3: in-chunk scan, write outputs ----------------
__global__ void scan_pass3(const unsigned int* __restrict__ P,
                           const float* __restrict__ Hinit,
                           float* __restrict__ out) {
  const int h = blockIdx.x * 256 + threadIdx.x;
  const int ch = blockIdx.y;
  const int b = blockIdx.z;
  float hs = Hinit[ch * (Bb * Hh) + b * Hh + h];
  const size_t base = ((size_t)(b * Tt + ch * CLEN)) * Hh + h;
  const unsigned int* p = P + base;
  float* o = out + base;
#pragma unroll 8
  for (int i = 0; i < CLEN; ++i) {
    const unsigned u = p[(size_t)i * Hh];
    hs = fmaf(bflo(u), hs, bfhi(u));
    o[(size_t)i * Hh] = hs;
  }
}

extern "C" void kernel_launch(void* const* d_in, const int* in_sizes, int n_in,
                              void* d_out, int out_size, void* d_ws, size_t ws_size,
                              hipStream_t stream) {
  const float* x  = (const float*)d_in[0];
  const float* h0 = (const float*)d_in[1];
  const float* Wz = (const float*)d_in[2];
  const float* bz = (const float*)d_in[3];
  const float* Wh = (const float*)d_in[4];
  const float* bh = (const float*)d_in[5];
  float* out = (float*)d_out;

  char* ws = (char*)d_ws;
  unsigned short* xb  = (unsigned short*)(ws);                       // 64 MiB
  unsigned short* wzb = (unsigned short*)(ws + 67108864);            // 2 MiB
  unsigned short* whb = (unsigned short*)(ws + 69206016);            // 2 MiB
  unsigned int*   P   = (unsigned int*)(ws + 71303168);              // 128 MiB
  float* Pp    = (float*)(ws + 205520896);                           // 1 MiB
  float* Qq    = (float*)(ws + 206569472);                           // 1 MiB
  float* Hinit = (float*)(ws + 207618048);                           // 1 MiB

  cvt_all_kernel<<<4096, 256, 0, stream>>>(x, Wz, Wh, xb, wzb, whb);

  gemm_kernel<<<2048, 512, 0, stream>>>(xb, wzb, whb, bz, bh, P, Pp, Qq);

  scan_pass2<<<Bb * Hh / 256, 256, 0, stream>>>(h0, Pp, Qq, Hinit);
  dim3 sgrid(Hh / 256, NCHUNK, Bb);
  scan_pass3<<<sgrid, 256, 0, stream>>>(P, Hinit, out);
}

// Round 11
// 258.585 us; speedup vs baseline: 1.2402x; 1.0016x over previous
//
#include <hip/hip_runtime.h>
#include <hip/hip_bf16.h>

#define Bb 8
#define Tt 4096
#define Dd 1024
#define Hh 1024
#define Mm (Bb * Tt)
#define NCHUNK 32
#define CLEN 128

typedef float f32x4 __attribute__((ext_vector_type(4)));
typedef short bf16x8 __attribute__((ext_vector_type(8)));

__device__ __forceinline__ unsigned f2bfu(float x) {
  unsigned u = __float_as_uint(x);
  return (u + 0x7fffu + ((u >> 16) & 1u)) >> 16;  // RNE to bf16 bits
}
__device__ __forceinline__ float bflo(unsigned u) { return __uint_as_float(u << 16); }
__device__ __forceinline__ float bfhi(unsigned u) { return __uint_as_float(u & 0xffff0000u); }

// ---------------- fp32 -> bf16 conversion, all three arrays, one launch ----
#define NX4 (Mm * Dd / 4)
#define NW4 (Hh * Dd / 4)
__global__ void cvt_all_kernel(const float* __restrict__ x,
                               const float* __restrict__ wz,
                               const float* __restrict__ wh,
                               unsigned short* __restrict__ xb,
                               unsigned short* __restrict__ wzb,
                               unsigned short* __restrict__ whb) {
  const int n4 = NX4 + 2 * NW4;
  int i = blockIdx.x * blockDim.x + threadIdx.x;
  const int stride = gridDim.x * blockDim.x;
  for (; i < n4; i += stride) {
    const float* src;
    unsigned short* dst;
    int j = i;
    if (j < NX4) {
      src = x; dst = xb;
    } else if (j < NX4 + NW4) {
      j -= NX4; src = wz; dst = wzb;
    } else {
      j -= NX4 + NW4; src = wh; dst = whb;
    }
    float4 v = reinterpret_cast<const float4*>(src)[j];
    ushort4 o;
    o.x = (unsigned short)f2bfu(v.x);
    o.y = (unsigned short)f2bfu(v.y);
    o.z = (unsigned short)f2bfu(v.z);
    o.w = (unsigned short)f2bfu(v.w);
    reinterpret_cast<ushort4*>(dst)[j] = o;
  }
}

__device__ __forceinline__ void async16(const unsigned short* g, unsigned short* l) {
  __builtin_amdgcn_global_load_lds(
      (const __attribute__((address_space(1))) unsigned int*)g,
      (__attribute__((address_space(3))) unsigned int*)l, 16, 0, 0);
}

// ordered affine compose across one lane-bit: segments (lo rows, hi rows)
#define SHFL_COMPOSE(A, Q, MASK, HIBIT)                                   \
  {                                                                       \
    const float pA_ = __shfl_xor(A, MASK);                                \
    const float pQ_ = __shfl_xor(Q, MASK);                                \
    const float Alo_ = (HIBIT) ? pA_ : A;                                 \
    const float Qlo_ = (HIBIT) ? pQ_ : Q;                                 \
    const float Ahi_ = (HIBIT) ? A : pA_;                                 \
    const float Qhi_ = (HIBIT) ? Q : pQ_;                                 \
    A = Alo_ * Ahi_;                                                      \
    Q = fmaf(Ahi_, Qlo_, Qhi_);                                           \
  }

// =====================================================================
// 128x256 tile, 8 waves (2M x 4N) of 64x64; acc 64 AGPR; 72 KiB LDS ->
// 2 blocks/CU. Counted vmcnt (stage 2-ahead), 1 barrier per K-step.
// Swizzle: R5 key (slot = (l4 + (row>>1)) & 3) - measured 0 bank
// conflicts (R6's row key measured 16.8M).
// Epilogue fuses gate transform + per-chunk scan reduction (pass1).
// =====================================================================
__global__ void __launch_bounds__(512, 4) gemm_kernel(
    const unsigned short* __restrict__ xb,
    const unsigned short* __restrict__ wzb,
    const unsigned short* __restrict__ whb,
    const float* __restrict__ bz,
    const float* __restrict__ bh,
    unsigned int* __restrict__ P,
    float* __restrict__ Pp, float* __restrict__ Qq) {
  __shared__ unsigned short lds[36864];  // 72 KiB
  const int tid = threadIdx.x;
  const int wid = tid >> 6;
  const int wm = wid >> 2;      // 0..1
  const int wn = wid & 3;       // 0..3
  const int l = tid & 63, ln = l & 15, l4 = l >> 4;

  // bijective XCD swizzle (nwg=2048, divisible by 8)
  const int id = blockIdx.x;
  const int sw = (id & 7) * 256 + (id >> 3);
  const int mb = sw >> 3, nb = sw & 7;
  const int m0 = mb * 128, h0 = nb * 128;

  // ---- staging constants: thread t -> row r0 = t>>2, LDS slot t&3;
  // slot s at row r holds global k-chunk (s - (r>>1))&3 ----
  const int r0 = tid >> 2;
  const int chunk = ((tid & 3) - (tid >> 3)) & 3;
  const unsigned short* agp = xb + (size_t)(m0 + r0) * Dd + chunk * 8;
  const int sub16 = r0 >> 4;
  const int hrow0 = h0 + ((sub16 >> 1) << 4) + (r0 & 15);
  const unsigned short* bgp =
      ((sub16 & 1) ? whb : wzb) + (size_t)hrow0 * Dd + chunk * 8;
  const int ta = tid * 8;

  auto stage = [&](int buf) {
    unsigned short* d = &lds[buf * 12288];
    async16(agp, d + ta);
    async16(bgp, d + 4096 + ta);
    async16(bgp + (size_t)64 * Dd, d + 8192 + ta);  // n+128 -> h+64
    agp += 32;
    bgp += 32;
  };

  // ---- fragment read offsets (shorts within a buf) ----
  int oA[4], oB[4];
#pragma unroll
  for (int mf = 0; mf < 4; ++mf) {
    const int row = wm * 64 + mf * 16 + ln;
    const int sl = (l4 + (row >> 1)) & 3;
    oA[mf] = row * 32 + sl * 8;
  }
#pragma unroll
  for (int nf = 0; nf < 4; ++nf) {
    const int row = wn * 64 + nf * 16 + ln;
    const int sl = (l4 + (row >> 1)) & 3;
    oB[nf] = 4096 + row * 32 + sl * 8;
  }

  f32x4 acc[4][4];
#pragma unroll
  for (int i = 0; i < 4; ++i)
#pragma unroll
    for (int j = 0; j < 4; ++j) acc[i][j] = f32x4{0.f, 0.f, 0.f, 0.f};

  // ---- prologue: stage buf0, buf1 (6 vmem ops) ----
  stage(0);
  stage(1);

  int cur = 0, nxt = 2;
#pragma unroll 1
  for (int s = 0; s < 32; ++s) {
    asm volatile("s_waitcnt vmcnt(3)" ::: "memory");  // buf[cur] ready
    __builtin_amdgcn_s_barrier();
    const unsigned short* bp = &lds[cur * 12288];
    bf16x8 af[4], bf[4];
    af[0] = *(const bf16x8*)(bp + oA[0]);
    af[1] = *(const bf16x8*)(bp + oA[1]);
    af[2] = *(const bf16x8*)(bp + oA[2]);
    af[3] = *(const bf16x8*)(bp + oA[3]);
    bf[0] = *(const bf16x8*)(bp + oB[0]);
    bf[1] = *(const bf16x8*)(bp + oB[1]);
    bf[2] = *(const bf16x8*)(bp + oB[2]);
    bf[3] = *(const bf16x8*)(bp + oB[3]);
    stage(nxt);  // overruns past k=1024 on last 2 steps: mapped, unused
    __builtin_amdgcn_s_setprio(1);
#pragma unroll
    for (int i = 0; i < 4; ++i)
#pragma unroll
      for (int j = 0; j < 4; ++j)
        acc[i][j] =
            __builtin_amdgcn_mfma_f32_16x16x32_bf16(af[i], bf[j], acc[i][j], 0, 0, 0);
    __builtin_amdgcn_s_setprio(0);
    cur = (cur + 1) == 3 ? 0 : cur + 1;
    nxt = (nxt + 1) == 3 ? 0 : nxt + 1;
  }

  // drain pending LDS-DMA (incl. overrun stages) then sync before LDS
  // scratch reuse: another wave's DMA may target buf regions.
  asm volatile("s_waitcnt vmcnt(0)" ::: "memory");
  __syncthreads();

  float* sA = (float*)lds;        // [2][128] per-wm chunk-half A
  float* sQ = (float*)lds + 256;  // [2][128] per-wm chunk-half Q
  const int b_idx = mb >> 5;      // batch
  const int ch = mb & 31;         // scan chunk within batch

  // Epilogue: C/D layout col=lane&15, row=(lane>>4)*4+q.
  // nf pair (2p, 2p+1) = (k, pre) for hcol = h0 + (wn*2+p)*16 + ln.
  // Also compose the 64-row affine (A,Q) per column (bf16-rounded a,c —
  // bit-identical to a pass1 over P).
#pragma unroll
  for (int p = 0; p < 2; ++p) {
    const int hcol = h0 + (wn * 2 + p) * 16 + ln;
    const float bzv = bz[hcol];
    const float bhv = bh[hcol];
    float Ar = 1.f, Qr = 0.f;
#pragma unroll
    for (int mf = 0; mf < 4; ++mf) {
      float A4 = 1.f, Q4 = 0.f;
#pragma unroll
      for (int q = 0; q < 4; ++q) {
        const int m = m0 + wm * 64 + mf * 16 + l4 * 4 + q;
        const float kv = acc[mf][2 * p][q] + bzv;
        const float pv = acc[mf][2 * p + 1][q] + bhv;
        const float ek = __expf(kv);
        const float a = 1.f / (1.f + ek);   // 1 - sigmoid(k)
        const float z = 1.f - a;            // sigmoid(k)
        const float g = (pv >= 0.f) ? (pv + 0.5f) : (1.f / (1.f + __expf(-pv)));
        const float c = z * g;
        const unsigned pw = f2bfu(a) | (f2bfu(c) << 16);
        P[(size_t)m * Hh + hcol] = pw;
        const float ar = bflo(pw), cr = bfhi(pw);
        Q4 = fmaf(ar, Q4, cr);  // rows ascending (q)
        A4 *= ar;
      }
      SHFL_COMPOSE(A4, Q4, 16, (l4 & 1));        // row bit2
      SHFL_COMPOSE(A4, Q4, 32, ((l4 >> 1) & 1)); // row bit3 -> seg16(mf)
      Qr = fmaf(A4, Qr, Q4);  // compose seg16s in mf order
      Ar *= A4;
    }
    if (l4 == 0) {
      sA[wm * 128 + (wn * 2 + p) * 16 + ln] = Ar;
      sQ[wm * 128 + (wn * 2 + p) * 16 + ln] = Qr;
    }
  }
  __syncthreads();
  if (tid < 128) {
    const float A0 = sA[tid], Q0 = sQ[tid];
    const float A1 = sA[128 + tid], Q1 = sQ[128 + tid];
    const int idx = ch * (Bb * Hh) + b_idx * Hh + (h0 + tid);
    Pp[idx] = A0 * A1;                 // rows 0-63 then 64-127
    Qq[idx] = fmaf(A1, Q0, Q1);
  }
}

// ---------------- scan pass 3 (pass2 fused): prefix + in-chunk scan ----------
// Per (ch,b) block: h_init = g(h0) composed through chunks 0..ch-1 via
// Pp/Qq (2 MB, L2-resident) — identical fmaf sequence to the old pass2,
// so bit-identical output. Then scan this chunk's 128 rows from P.
__global__ void scan_pass3(const unsigned int* __restrict__ P,
                           const float* __restrict__ Pp, const float* __restrict__ Qq,
                           const float* __restrict__ h0raw,
                           float* __restrict__ out) {
  const int h = blockIdx.x * 256 + threadIdx.x;
  const int ch = blockIdx.y;
  const int b = blockIdx.z;
  const float x = h0raw[b * Hh + h];
  float hs = (x >= 0.f) ? (x + 0.5f) : (1.f / (1.f + __expf(-x)));  // g(h_0)
#pragma unroll 4
  for (int c = 0; c < ch; ++c) {
    const int idx = c * (Bb * Hh) + b * Hh + h;
    hs = fmaf(Pp[idx], hs, Qq[idx]);
  }
  const size_t base = ((size_t)(b * Tt + ch * CLEN)) * Hh + h;
  const unsigned int* p = P + base;
  float* o = out + base;
#pragma unroll 8
  for (int i = 0; i < CLEN; ++i) {
    const unsigned u = p[(size_t)i * Hh];
    hs = fmaf(bflo(u), hs, bfhi(u));
    o[(size_t)i * Hh] = hs;
  }
}

extern "C" void kernel_launch(void* const* d_in, const int* in_sizes, int n_in,
                              void* d_out, int out_size, void* d_ws, size_t ws_size,
                              hipStream_t stream) {
  const float* x  = (const float*)d_in[0];
  const float* h0 = (const float*)d_in[1];
  const float* Wz = (const float*)d_in[2];
  const float* bz = (const float*)d_in[3];
  const float* Wh = (const float*)d_in[4];
  const float* bh = (const float*)d_in[5];
  float* out = (float*)d_out;

  char* ws = (char*)d_ws;
  unsigned short* xb  = (unsigned short*)(ws);                       // 64 MiB
  unsigned short* wzb = (unsigned short*)(ws + 67108864);            // 2 MiB
  unsigned short* whb = (unsigned short*)(ws + 69206016);            // 2 MiB
  unsigned int*   P   = (unsigned int*)(ws + 71303168);              // 128 MiB
  float* Pp    = (float*)(ws + 205520896);                           // 1 MiB
  float* Qq    = (float*)(ws + 206569472);                           // 1 MiB

  cvt_all_kernel<<<4096, 256, 0, stream>>>(x, Wz, Wh, xb, wzb, whb);

  gemm_kernel<<<2048, 512, 0, stream>>>(xb, wzb, whb, bz, bh, P, Pp, Qq);

  dim3 sgrid(Hh / 256, NCHUNK, Bb);
  scan_pass3<<<sgrid, 256, 0, stream>>>(P, Pp, Qq, h0, out);
}